// Round 6
// baseline (353.420 us; speedup 1.0000x reference)
//
#include <hip/hip_runtime.h>

#define HIDDEN 128
#define SCAN_B 1024

typedef float v2f __attribute__((ext_vector_type(2)));
__device__ __forceinline__ v2f v2s(float a) { v2f r; r.x = a; r.y = a; return r; }

// ================= CSR build (per call; no fp atomics anywhere) =============
__global__ __launch_bounds__(256)
void k_hist(const int* __restrict__ dst, int* __restrict__ cnt,
            int* __restrict__ rank, int E) {
    int e = blockIdx.x * 256 + threadIdx.x;
    if (e < E) rank[e] = atomicAdd(&cnt[dst[e]], 1);
}

__global__ __launch_bounds__(SCAN_B)
void k_scan1(const int* __restrict__ cnt, int* __restrict__ offs,
             int* __restrict__ bsum, int N) {
    __shared__ int sm[SCAN_B];
    int g = blockIdx.x * SCAN_B + threadIdx.x;
    int v = (g < N) ? cnt[g] : 0;
    int acc = v;
    sm[threadIdx.x] = v;
    __syncthreads();
    for (int d = 1; d < SCAN_B; d <<= 1) {
        int t = (threadIdx.x >= d) ? sm[threadIdx.x - d] : 0;
        __syncthreads();
        acc += t;
        sm[threadIdx.x] = acc;
        __syncthreads();
    }
    if (g < N) offs[g] = acc - v;                 // exclusive
    if (threadIdx.x == SCAN_B - 1) bsum[blockIdx.x] = acc;
}

__global__ __launch_bounds__(SCAN_B)
void k_scan2(int* __restrict__ bsum, int nb) {
    __shared__ int sm[SCAN_B];
    int v = (threadIdx.x < nb) ? bsum[threadIdx.x] : 0;
    int acc = v;
    sm[threadIdx.x] = v;
    __syncthreads();
    for (int d = 1; d < SCAN_B; d <<= 1) {
        int t = (threadIdx.x >= d) ? sm[threadIdx.x - d] : 0;
        __syncthreads();
        acc += t;
        sm[threadIdx.x] = acc;
        __syncthreads();
    }
    if (threadIdx.x < nb) bsum[threadIdx.x] = acc - v;   // exclusive
}

__global__ __launch_bounds__(SCAN_B)
void k_scan3(int* __restrict__ offs, const int* __restrict__ bsum, int N) {
    int g = blockIdx.x * SCAN_B + threadIdx.x;
    if (g < N) offs[g] += bsum[blockIdx.x];
}

// Scatter edges into CSR order. One 8B packed store per edge (src, w).
__global__ __launch_bounds__(256)
void k_fill(const int* __restrict__ src, const int* __restrict__ dst,
            const float* __restrict__ ew, const int* __restrict__ offs,
            const int* __restrict__ rank, int2* __restrict__ cpack, int E) {
    int e = blockIdx.x * 256 + threadIdx.x;
    if (e >= E) return;
    int d = dst[e];
    int slot = offs[d] + rank[e];
    int2 p;
    p.x = src[e];
    p.y = __float_as_int(ew[e]);
    cpack[slot] = p;
}

__device__ __forceinline__ int end_of(const int* offs, int i, int N, int E) {
    return (i + 1 < N) ? offs[i + 1] : E;
}

// ================= layer 1: gather 2ch, emit combined y = (a0,a1,x0,x1) ====
__global__ __launch_bounds__(256)
void k_gather2(const int* __restrict__ offs, const int2* __restrict__ cpack,
               const float* __restrict__ x, float4* __restrict__ yv,
               int N, int E) {
    int i = blockIdx.x * 256 + threadIdx.x;
    if (i >= N) return;
    int start = offs[i], end = end_of(offs, i, N, E);
    float a0 = 0.f, a1 = 0.f;
    for (int j = start; j < end; ++j) {
        int2  p = cpack[j];
        int   s = p.x;
        float w = __int_as_float(p.y);
        float2 xv = *reinterpret_cast<const float2*>(x + (size_t)s * 2);
        a0 = fmaf(w, xv.x, a0);
        a1 = fmaf(w, xv.y, a1);
    }
    float2 xi = *reinterpret_cast<const float2*>(x + (size_t)i * 2);
    yv[i] = make_float4(a0, a1, xi.x, xi.y);
}

// ================= fused layer-2 aggregation + layer-1 node update ==========
// (R5 structure — per-lane staging + shfl + 4-edge unroll + packed v2f math)
__global__ __launch_bounds__(256)
void k_gatherfused(const int* __restrict__ offs, const int2* __restrict__ cpack,
                   const float4* __restrict__ yv,
                   const float* __restrict__ W1rel, const float* __restrict__ b1,
                   const float* __restrict__ W1root,
                   float* __restrict__ h, float* __restrict__ aggr,
                   int N, int E) {
    int wv   = (blockIdx.x * 256 + threadIdx.x) >> 6;
    int lane = threadIdx.x & 63;
    if (wv >= N) return;

    const int c0 = lane * 2;
    const v2f WR0 = *reinterpret_cast<const v2f*>(W1rel  + c0);
    const v2f WR1 = *reinterpret_cast<const v2f*>(W1rel  + HIDDEN + c0);
    const v2f WO0 = *reinterpret_cast<const v2f*>(W1root + c0);
    const v2f WO1 = *reinterpret_cast<const v2f*>(W1root + HIDDEN + c0);
    const v2f B   = *reinterpret_cast<const v2f*>(b1 + c0);
    const v2f Z   = {0.f, 0.f};

    int start = offs[wv], end = end_of(offs, wv, N, E);
    v2f acc = {0.f, 0.f};

    for (int base = start; base < end; base += 64) {
        int nb = min(64, end - base);
        int sx = 0, wb = 0;
        if (lane < nb) {                       // one coalesced 8B/lane load
            int2 p = cpack[base + lane];
            sx = p.x; wb = p.y;
        }
        int k = 0;
        for (; k + 4 <= nb; k += 4) {
            int s0 = __shfl(sx, k);
            int s1 = __shfl(sx, k + 1);
            int s2 = __shfl(sx, k + 2);
            int s3 = __shfl(sx, k + 3);
            float w0 = __int_as_float(__shfl(wb, k));
            float w1 = __int_as_float(__shfl(wb, k + 1));
            float w2 = __int_as_float(__shfl(wb, k + 2));
            float w3 = __int_as_float(__shfl(wb, k + 3));
            float4 y0 = yv[s0];                // 4 independent L2 loads in flight
            float4 y1 = yv[s1];
            float4 y2 = yv[s2];
            float4 y3 = yv[s3];

            v2f t0 = B + v2s(y0.x) * WR0 + v2s(y0.y) * WR1
                       + v2s(y0.z) * WO0 + v2s(y0.w) * WO1;
            v2f t1 = B + v2s(y1.x) * WR0 + v2s(y1.y) * WR1
                       + v2s(y1.z) * WO0 + v2s(y1.w) * WO1;
            v2f t2 = B + v2s(y2.x) * WR0 + v2s(y2.y) * WR1
                       + v2s(y2.z) * WO0 + v2s(y2.w) * WO1;
            v2f t3 = B + v2s(y3.x) * WR0 + v2s(y3.y) * WR1
                       + v2s(y3.z) * WO0 + v2s(y3.w) * WO1;
            t0 = __builtin_elementwise_max(t0, Z);
            t1 = __builtin_elementwise_max(t1, Z);
            t2 = __builtin_elementwise_max(t2, Z);
            t3 = __builtin_elementwise_max(t3, Z);
            acc = acc + v2s(w0) * t0;
            acc = acc + v2s(w1) * t1;
            acc = acc + v2s(w2) * t2;
            acc = acc + v2s(w3) * t3;
        }
        for (; k < nb; ++k) {                  // tail (<=3 edges)
            int   s0 = __shfl(sx, k);
            float w0 = __int_as_float(__shfl(wb, k));
            float4 y0 = yv[s0];
            v2f t0 = B + v2s(y0.x) * WR0 + v2s(y0.y) * WR1
                       + v2s(y0.z) * WO0 + v2s(y0.w) * WO1;
            t0 = __builtin_elementwise_max(t0, Z);
            acc = acc + v2s(w0) * t0;
        }
    }

    *reinterpret_cast<v2f*>(aggr + (size_t)wv * HIDDEN + c0) = acc;

    // fused k_node1: this wave's own h1 row
    {
        float4 y = yv[wv];
        v2f t = B + v2s(y.x) * WR0 + v2s(y.y) * WR1
                  + v2s(y.z) * WO0 + v2s(y.w) * WO1;
        t = __builtin_elementwise_max(t, Z);
        *reinterpret_cast<v2f*>(h + (size_t)wv * HIDDEN + c0) = t;
    }
}

// ============ fused layer-2 node update + layer-3 projection ================
// h2 = relu([aggr | h] @ [W2rel ; W2root] + b2)  (kept in registers only)
// z  = h2 @ W3rel ; out = h2 @ W3root + b3       (h2 never stored!)
// BM=128 nodes x BN=128 ch per block, BK=64, 256 threads; thread = 8 nodes
// (rows m*16+ri, m=0..7) x 8 ch (ci*4.., 64+ci*4..). The m*16+ri row map
// keeps the 4 ri-groups of a wave on banks {+0,+4,+8,+12} — consecutive-row
// mapping would be 4-way same-bank (8*68 == 0 mod 32).
#define BM2 128
#define XS_STRIDE 68

__global__ __launch_bounds__(256)
void k_node2(const float* __restrict__ aggr, const float* __restrict__ h,
             const float* __restrict__ Wrel, const float* __restrict__ b,
             const float* __restrict__ Wroot,
             const float* __restrict__ W3rel, const float* __restrict__ b3,
             const float* __restrict__ W3root,
             float* __restrict__ z, float* __restrict__ out, int N) {
    __shared__ float Xs[BM2 * XS_STRIDE];     // 128 x 64 input tile (+pad) 34.8KB
    __shared__ float Ws[64 * HIDDEN];         // 64 x 128 weight tile       32.8KB
    __shared__ float W3s[HIDDEN * 6];         // [k][0..2]=W3rel, [3..5]=W3root 3KB

    const int tid = threadIdx.x;
    const int ci  = tid & 15;                 // channel group: cols ci*4, 64+ci*4
    const int ri  = tid >> 4;                 // row residue: rows m*16+ri
    const int nb  = blockIdx.x * BM2;

    // preload W3 (tiny, once) — ordered by the first __syncthreads below
    if (tid < HIDDEN) {
#pragma unroll
        for (int c = 0; c < 3; ++c) {
            W3s[tid * 6 + c]     = W3rel [tid * 3 + c];
            W3s[tid * 6 + 3 + c] = W3root[tid * 3 + c];
        }
    }

    float acc[8][8];
    {
        float4 b0 = *reinterpret_cast<const float4*>(b + ci * 4);
        float4 b1 = *reinterpret_cast<const float4*>(b + 64 + ci * 4);
#pragma unroll
        for (int m = 0; m < 8; ++m) {
            acc[m][0] = b0.x; acc[m][1] = b0.y; acc[m][2] = b0.z; acc[m][3] = b0.w;
            acc[m][4] = b1.x; acc[m][5] = b1.y; acc[m][6] = b1.z; acc[m][7] = b1.w;
        }
    }

    // K = 256 total: tiles 0,1 = aggr @ Wrel; tiles 2,3 = h @ Wroot.
    for (int t = 0; t < 4; ++t) {
        const float* Xsrc = (t < 2) ? aggr : h;
        const float* Wsrc = (t < 2) ? Wrel : Wroot;
        const int kc = (t & 1) * 64;

        __syncthreads();                      // previous compute done before overwrite
        // stage X tile: 128 rows x 64 cols, 8 float4/thread (coalesced 256B rows)
#pragma unroll
        for (int q = 0; q < 8; ++q) {
            int idx = q * 256 + tid;          // 0..2047
            int row = idx >> 4;
            int c4  = (idx & 15) * 4;
            int gr  = nb + row; if (gr >= N) gr = N - 1;
            float4 v = *reinterpret_cast<const float4*>(Xsrc + (size_t)gr * HIDDEN + kc + c4);
            *reinterpret_cast<float4*>(&Xs[row * XS_STRIDE + c4]) = v;
        }
        // stage W tile: rows kc..kc+63 of [128][128], 8 float4/thread
#pragma unroll
        for (int q = 0; q < 8; ++q) {
            int idx = q * 256 + tid;          // 0..2047
            int row = idx >> 5;
            int c4  = (idx & 31) * 4;
            float4 v = *reinterpret_cast<const float4*>(Wsrc + (size_t)(kc + row) * HIDDEN + c4);
            *reinterpret_cast<float4*>(&Ws[row * HIDDEN + c4]) = v;
        }
        __syncthreads();

        // compute: 64 k-steps, unrolled by 4 with float4 LDS reads
#pragma unroll
        for (int kk = 0; kk < 64; kk += 4) {
            float4 xr[8];
#pragma unroll
            for (int m = 0; m < 8; ++m)
                xr[m] = *reinterpret_cast<const float4*>(&Xs[(m * 16 + ri) * XS_STRIDE + kk]);
#pragma unroll
            for (int j = 0; j < 4; ++j) {
                float4 w0 = *reinterpret_cast<const float4*>(&Ws[(kk + j) * HIDDEN + ci * 4]);
                float4 w1 = *reinterpret_cast<const float4*>(&Ws[(kk + j) * HIDDEN + 64 + ci * 4]);
#pragma unroll
                for (int m = 0; m < 8; ++m) {
                    float xm = (j == 0) ? xr[m].x : (j == 1) ? xr[m].y
                             : (j == 2) ? xr[m].z : xr[m].w;
                    acc[m][0] = fmaf(xm, w0.x, acc[m][0]);
                    acc[m][1] = fmaf(xm, w0.y, acc[m][1]);
                    acc[m][2] = fmaf(xm, w0.z, acc[m][2]);
                    acc[m][3] = fmaf(xm, w0.w, acc[m][3]);
                    acc[m][4] = fmaf(xm, w1.x, acc[m][4]);
                    acc[m][5] = fmaf(xm, w1.y, acc[m][5]);
                    acc[m][6] = fmaf(xm, w1.z, acc[m][6]);
                    acc[m][7] = fmaf(xm, w1.w, acc[m][7]);
                }
            }
        }
    }

    // epilogue: relu -> per-thread rank-8 partials vs W3 -> width-16 shfl
    // reduce over the 16 ci-threads of each node -> z / out (h2 never stored)
    const float b30 = b3[0], b31 = b3[1], b32 = b3[2];
#pragma unroll
    for (int m = 0; m < 8; ++m) {
        int node = nb + m * 16 + ri;
        float zr0 = 0.f, zr1 = 0.f, zr2 = 0.f;
        float zo0 = 0.f, zo1 = 0.f, zo2 = 0.f;
#pragma unroll
        for (int jj = 0; jj < 4; ++jj) {
            float hv = fmaxf(acc[m][jj], 0.f);
            const float* w3 = &W3s[(ci * 4 + jj) * 6];
            zr0 = fmaf(hv, w3[0], zr0); zr1 = fmaf(hv, w3[1], zr1); zr2 = fmaf(hv, w3[2], zr2);
            zo0 = fmaf(hv, w3[3], zo0); zo1 = fmaf(hv, w3[4], zo1); zo2 = fmaf(hv, w3[5], zo2);
        }
#pragma unroll
        for (int jj = 0; jj < 4; ++jj) {
            float hv = fmaxf(acc[m][4 + jj], 0.f);
            const float* w3 = &W3s[(64 + ci * 4 + jj) * 6];
            zr0 = fmaf(hv, w3[0], zr0); zr1 = fmaf(hv, w3[1], zr1); zr2 = fmaf(hv, w3[2], zr2);
            zo0 = fmaf(hv, w3[3], zo0); zo1 = fmaf(hv, w3[4], zo1); zo2 = fmaf(hv, w3[5], zo2);
        }
#pragma unroll
        for (int d = 8; d >= 1; d >>= 1) {
            zr0 += __shfl_down(zr0, d, 16);
            zr1 += __shfl_down(zr1, d, 16);
            zr2 += __shfl_down(zr2, d, 16);
            zo0 += __shfl_down(zo0, d, 16);
            zo1 += __shfl_down(zo1, d, 16);
            zo2 += __shfl_down(zo2, d, 16);
        }
        if (ci == 0 && node < N) {
            z[(size_t)node * 3 + 0] = zr0;
            z[(size_t)node * 3 + 1] = zr1;
            z[(size_t)node * 3 + 2] = zr2;
            out[(size_t)node * 3 + 0] = zo0 + b30;
            out[(size_t)node * 3 + 1] = zo1 + b31;
            out[(size_t)node * 3 + 2] = zo2 + b32;
        }
    }
}

// ================= layer 3 gather =====================
__global__ __launch_bounds__(256)
void k_gather3(const int* __restrict__ offs, const int2* __restrict__ cpack,
               const float* __restrict__ z, float* __restrict__ out,
               int N, int E) {
    int i = blockIdx.x * 256 + threadIdx.x;
    if (i >= N) return;
    int start = offs[i], end = end_of(offs, i, N, E);
    float a0 = 0.f, a1 = 0.f, a2 = 0.f;
    for (int j = start; j < end; ++j) {
        int2  p = cpack[j];
        int   s = p.x;
        float w = __int_as_float(p.y);
        const float* zp = z + (size_t)s * 3;
        a0 = fmaf(w, zp[0], a0);
        a1 = fmaf(w, zp[1], a1);
        a2 = fmaf(w, zp[2], a2);
    }
    out[(size_t)i * 3 + 0] += a0;
    out[(size_t)i * 3 + 1] += a1;
    out[(size_t)i * 3 + 2] += a2;
}

extern "C" void kernel_launch(void* const* d_in, const int* in_sizes, int n_in,
                              void* d_out, int out_size, void* d_ws, size_t ws_size,
                              hipStream_t stream) {
    const float* x      = (const float*)d_in[0];
    const int*   ei     = (const int*)  d_in[1];
    const float* ew     = (const float*)d_in[2];
    const float* W1rel  = (const float*)d_in[4];
    const float* b1     = (const float*)d_in[5];
    const float* W1root = (const float*)d_in[6];
    const float* W2rel  = (const float*)d_in[7];
    const float* b2     = (const float*)d_in[8];
    const float* W2root = (const float*)d_in[9];
    const float* W3rel  = (const float*)d_in[10];
    const float* b3     = (const float*)d_in[11];
    const float* W3root = (const float*)d_in[12];
    float* out = (float*)d_out;

    const int N = in_sizes[0] / 2;
    const int E = in_sizes[2];
    const int* src = ei;
    const int* dst = ei + E;

    // -------- workspace layout --------
    // h     : N*128 f32   (h1; front E ints alias rank during CSR build)
    // aggr  : N*128 f32   (layer-2 aggregation; read-only in node2)
    // offs  : N int | bsum : SCAN_B int
    // cpack : E int2      (front N ints alias cnt — cnt dead before k_fill)
    // yv    : N float4    (combined (aggr1,x); dead after gatherfused —
    //         front N*3 f32 reused as z by node2/gather3)
    float* h    = (float*)d_ws;
    float* aggr = h + (size_t)N * HIDDEN;
    int*   offs = (int*)(aggr + (size_t)N * HIDDEN);
    int*   bsum = offs + N;
    size_t cpo  = (size_t)(bsum + SCAN_B - (int*)d_ws);
    cpo = (cpo + 1) & ~(size_t)1;          // 8B alignment
    int2*   cpack = (int2*)((int*)d_ws + cpo);
    size_t yvo  = (size_t)((char*)(cpack + E) - (char*)d_ws);
    yvo = (yvo + 15) & ~(size_t)15;        // 16B alignment
    float4* yv  = (float4*)((char*)d_ws + yvo);
    int* cnt  = (int*)cpack;               // alias: dead before k_fill writes cpack
    int* rank = (int*)h;                   // alias: dead before gatherfused writes h
    float* z  = (float*)yv;                // alias: yv dead after gatherfused

    const int nbScan = (N + SCAN_B - 1) / SCAN_B;

    // -------- CSR build --------
    hipMemsetAsync(cnt, 0, (size_t)N * sizeof(int), stream);
    k_hist <<<(E + 255) / 256, 256, 0, stream>>>(dst, cnt, rank, E);
    k_scan1<<<nbScan, SCAN_B, 0, stream>>>(cnt, offs, bsum, N);
    k_scan2<<<1, SCAN_B, 0, stream>>>(bsum, nbScan);
    k_scan3<<<nbScan, SCAN_B, 0, stream>>>(offs, bsum, N);
    k_fill <<<(E + 255) / 256, 256, 0, stream>>>(src, dst, ew, offs, rank, cpack, E);

    // -------- layer 1 aggregation (2ch) + y pack --------
    k_gather2<<<(N + 255) / 256, 256, 0, stream>>>(offs, cpack, x, yv, N, E);

    // -------- fused layer-2 aggregation + layer-1 node update --------
    {
        long long threads = (long long)N * 64;
        k_gatherfused<<<(int)((threads + 255) / 256), 256, 0, stream>>>(
            offs, cpack, yv, W1rel, b1, W1root, h, aggr, N, E);
    }

    // -------- fused layer-2 node update + layer-3 projection --------
    k_node2<<<(N + BM2 - 1) / BM2, 256, 0, stream>>>(
        aggr, h, W2rel, b2, W2root, W3rel, b3, W3root, z, out, N);

    // -------- layer 3 gather --------
    k_gather3<<<(N + 255) / 256, 256, 0, stream>>>(offs, cpack, z, out, N, E);
}

// Round 7
// 317.349 us; speedup vs baseline: 1.1137x; 1.1137x over previous
//
#include <hip/hip_runtime.h>

#define HIDDEN 128
#define SCAN_B 1024

typedef float v2f __attribute__((ext_vector_type(2)));
__device__ __forceinline__ v2f v2s(float a) { v2f r; r.x = a; r.y = a; return r; }

// ================= CSR build (per call; no fp atomics anywhere) =============
__global__ __launch_bounds__(256)
void k_hist(const int* __restrict__ dst, int* __restrict__ cnt,
            int* __restrict__ rank, int E) {
    int e = blockIdx.x * 256 + threadIdx.x;
    if (e < E) rank[e] = atomicAdd(&cnt[dst[e]], 1);
}

__global__ __launch_bounds__(SCAN_B)
void k_scan1(const int* __restrict__ cnt, int* __restrict__ offs,
             int* __restrict__ bsum, int N) {
    __shared__ int sm[SCAN_B];
    int g = blockIdx.x * SCAN_B + threadIdx.x;
    int v = (g < N) ? cnt[g] : 0;
    int acc = v;
    sm[threadIdx.x] = v;
    __syncthreads();
    for (int d = 1; d < SCAN_B; d <<= 1) {
        int t = (threadIdx.x >= d) ? sm[threadIdx.x - d] : 0;
        __syncthreads();
        acc += t;
        sm[threadIdx.x] = acc;
        __syncthreads();
    }
    if (g < N) offs[g] = acc - v;                 // exclusive
    if (threadIdx.x == SCAN_B - 1) bsum[blockIdx.x] = acc;
}

__global__ __launch_bounds__(SCAN_B)
void k_scan2(int* __restrict__ bsum, int nb) {
    __shared__ int sm[SCAN_B];
    int v = (threadIdx.x < nb) ? bsum[threadIdx.x] : 0;
    int acc = v;
    sm[threadIdx.x] = v;
    __syncthreads();
    for (int d = 1; d < SCAN_B; d <<= 1) {
        int t = (threadIdx.x >= d) ? sm[threadIdx.x - d] : 0;
        __syncthreads();
        acc += t;
        sm[threadIdx.x] = acc;
        __syncthreads();
    }
    if (threadIdx.x < nb) bsum[threadIdx.x] = acc - v;   // exclusive
}

__global__ __launch_bounds__(SCAN_B)
void k_scan3(int* __restrict__ offs, const int* __restrict__ bsum, int N) {
    int g = blockIdx.x * SCAN_B + threadIdx.x;
    if (g < N) offs[g] += bsum[blockIdx.x];
}

// Scatter edges into CSR order. One 8B packed store per edge (src, w).
__global__ __launch_bounds__(256)
void k_fill(const int* __restrict__ src, const int* __restrict__ dst,
            const float* __restrict__ ew, const int* __restrict__ offs,
            const int* __restrict__ rank, int2* __restrict__ cpack, int E) {
    int e = blockIdx.x * 256 + threadIdx.x;
    if (e >= E) return;
    int d = dst[e];
    int slot = offs[d] + rank[e];
    int2 p;
    p.x = src[e];
    p.y = __float_as_int(ew[e]);
    cpack[slot] = p;
}

__device__ __forceinline__ int end_of(const int* offs, int i, int N, int E) {
    return (i + 1 < N) ? offs[i + 1] : E;
}

// ================= layer 1: gather 2ch, emit combined y = (a0,a1,x0,x1) ====
__global__ __launch_bounds__(256)
void k_gather2(const int* __restrict__ offs, const int2* __restrict__ cpack,
               const float* __restrict__ x, float4* __restrict__ yv,
               int N, int E) {
    int i = blockIdx.x * 256 + threadIdx.x;
    if (i >= N) return;
    int start = offs[i], end = end_of(offs, i, N, E);
    float a0 = 0.f, a1 = 0.f;
    for (int j = start; j < end; ++j) {
        int2  p = cpack[j];
        int   s = p.x;
        float w = __int_as_float(p.y);
        float2 xv = *reinterpret_cast<const float2*>(x + (size_t)s * 2);
        a0 = fmaf(w, xv.x, a0);
        a1 = fmaf(w, xv.y, a1);
    }
    float2 xi = *reinterpret_cast<const float2*>(x + (size_t)i * 2);
    yv[i] = make_float4(a0, a1, xi.x, xi.y);
}

// ================= fused layer-2 aggregation + layer-1 node update ==========
// (R5 structure — per-lane staging + shfl + 4-edge unroll + packed v2f math)
__global__ __launch_bounds__(256)
void k_gatherfused(const int* __restrict__ offs, const int2* __restrict__ cpack,
                   const float4* __restrict__ yv,
                   const float* __restrict__ W1rel, const float* __restrict__ b1,
                   const float* __restrict__ W1root,
                   float* __restrict__ h, float* __restrict__ aggr,
                   int N, int E) {
    int wv   = (blockIdx.x * 256 + threadIdx.x) >> 6;
    int lane = threadIdx.x & 63;
    if (wv >= N) return;

    const int c0 = lane * 2;
    const v2f WR0 = *reinterpret_cast<const v2f*>(W1rel  + c0);
    const v2f WR1 = *reinterpret_cast<const v2f*>(W1rel  + HIDDEN + c0);
    const v2f WO0 = *reinterpret_cast<const v2f*>(W1root + c0);
    const v2f WO1 = *reinterpret_cast<const v2f*>(W1root + HIDDEN + c0);
    const v2f B   = *reinterpret_cast<const v2f*>(b1 + c0);
    const v2f Z   = {0.f, 0.f};

    int start = offs[wv], end = end_of(offs, wv, N, E);
    v2f acc = {0.f, 0.f};

    for (int base = start; base < end; base += 64) {
        int nb = min(64, end - base);
        int sx = 0, wb = 0;
        if (lane < nb) {                       // one coalesced 8B/lane load
            int2 p = cpack[base + lane];
            sx = p.x; wb = p.y;
        }
        int k = 0;
        for (; k + 4 <= nb; k += 4) {
            int s0 = __shfl(sx, k);
            int s1 = __shfl(sx, k + 1);
            int s2 = __shfl(sx, k + 2);
            int s3 = __shfl(sx, k + 3);
            float w0 = __int_as_float(__shfl(wb, k));
            float w1 = __int_as_float(__shfl(wb, k + 1));
            float w2 = __int_as_float(__shfl(wb, k + 2));
            float w3 = __int_as_float(__shfl(wb, k + 3));
            float4 y0 = yv[s0];                // 4 independent L2 loads in flight
            float4 y1 = yv[s1];
            float4 y2 = yv[s2];
            float4 y3 = yv[s3];

            v2f t0 = B + v2s(y0.x) * WR0 + v2s(y0.y) * WR1
                       + v2s(y0.z) * WO0 + v2s(y0.w) * WO1;
            v2f t1 = B + v2s(y1.x) * WR0 + v2s(y1.y) * WR1
                       + v2s(y1.z) * WO0 + v2s(y1.w) * WO1;
            v2f t2 = B + v2s(y2.x) * WR0 + v2s(y2.y) * WR1
                       + v2s(y2.z) * WO0 + v2s(y2.w) * WO1;
            v2f t3 = B + v2s(y3.x) * WR0 + v2s(y3.y) * WR1
                       + v2s(y3.z) * WO0 + v2s(y3.w) * WO1;
            t0 = __builtin_elementwise_max(t0, Z);
            t1 = __builtin_elementwise_max(t1, Z);
            t2 = __builtin_elementwise_max(t2, Z);
            t3 = __builtin_elementwise_max(t3, Z);
            acc = acc + v2s(w0) * t0;
            acc = acc + v2s(w1) * t1;
            acc = acc + v2s(w2) * t2;
            acc = acc + v2s(w3) * t3;
        }
        for (; k < nb; ++k) {                  // tail (<=3 edges)
            int   s0 = __shfl(sx, k);
            float w0 = __int_as_float(__shfl(wb, k));
            float4 y0 = yv[s0];
            v2f t0 = B + v2s(y0.x) * WR0 + v2s(y0.y) * WR1
                       + v2s(y0.z) * WO0 + v2s(y0.w) * WO1;
            t0 = __builtin_elementwise_max(t0, Z);
            acc = acc + v2s(w0) * t0;
        }
    }

    *reinterpret_cast<v2f*>(aggr + (size_t)wv * HIDDEN + c0) = acc;

    // fused k_node1: this wave's own h1 row
    {
        float4 y = yv[wv];
        v2f t = B + v2s(y.x) * WR0 + v2s(y.y) * WR1
                  + v2s(y.z) * WO0 + v2s(y.w) * WO1;
        t = __builtin_elementwise_max(t, Z);
        *reinterpret_cast<v2f*>(h + (size_t)wv * HIDDEN + c0) = t;
    }
}

// ============ fused layer-2 node update + layer-3 projection ================
// R5's proven BM=64 GEMM geometry (92 VGPR, 3 blocks/CU, 0 bank conflicts),
// with R6's h2-never-stored fusion but a FIXED epilogue:
//   - W3 staged in LDS with stride 7 (2-way max -> free; R6's stride 6 was
//     a 4-way conflict, 3.35M conflict cycles)
//   - acc stays [4][8]  -> no VGPR/occupancy regression
// h2 = relu([aggr | h] @ [W2rel ; W2root] + b2)   (registers only)
// z  = h2 @ W3rel ; out = h2 @ W3root + b3
#define BM2 64
#define XS_STRIDE 68   // 64 + 4 pad: float4 alignment + bank spread
#define W3_STRIDE 7    // stride 6 -> 4-way bank conflict; 7 -> 2-way (free)

__global__ __launch_bounds__(256)
void k_node2(const float* __restrict__ aggr, const float* __restrict__ h,
             const float* __restrict__ Wrel, const float* __restrict__ b,
             const float* __restrict__ Wroot,
             const float* __restrict__ W3rel, const float* __restrict__ b3,
             const float* __restrict__ W3root,
             float* __restrict__ z, float* __restrict__ out, int N) {
    __shared__ float Xs[BM2 * XS_STRIDE];     // 64 x 64 input tile (+pad) 17.4KB
    __shared__ float Ws[64 * HIDDEN];         // 64 x 128 weight tile      32.8KB
    __shared__ float W3s[HIDDEN * W3_STRIDE]; // [k][0..2]=W3rel,[3..5]=W3root 3.6KB

    const int tid = threadIdx.x;
    const int ci  = tid & 15;                 // channel group: cols ci*4, 64+ci*4
    const int ri  = tid >> 4;                 // node group: rows ri*4 .. ri*4+3
    const int nb  = blockIdx.x * BM2;

    // preload W3 (tiny, once) — ordered by the first __syncthreads below
    if (tid < HIDDEN) {
#pragma unroll
        for (int c = 0; c < 3; ++c) {
            W3s[tid * W3_STRIDE + c]     = W3rel [tid * 3 + c];
            W3s[tid * W3_STRIDE + 3 + c] = W3root[tid * 3 + c];
        }
    }

    float acc[4][8];
    {
        float4 b0 = *reinterpret_cast<const float4*>(b + ci * 4);
        float4 b1 = *reinterpret_cast<const float4*>(b + 64 + ci * 4);
#pragma unroll
        for (int m = 0; m < 4; ++m) {
            acc[m][0] = b0.x; acc[m][1] = b0.y; acc[m][2] = b0.z; acc[m][3] = b0.w;
            acc[m][4] = b1.x; acc[m][5] = b1.y; acc[m][6] = b1.z; acc[m][7] = b1.w;
        }
    }

    // K = 256 total: tiles 0,1 = aggr @ Wrel; tiles 2,3 = h @ Wroot.
    for (int t = 0; t < 4; ++t) {
        const float* Xsrc = (t < 2) ? aggr : h;
        const float* Wsrc = (t < 2) ? Wrel : Wroot;
        const int kc = (t & 1) * 64;

        __syncthreads();                      // previous compute done before overwrite
#pragma unroll
        for (int q = 0; q < 4; ++q) {
            int idx = q * 256 + tid;          // 0..1023
            int row = idx >> 4;
            int c4  = (idx & 15) * 4;
            int gr  = nb + row; if (gr >= N) gr = N - 1;
            float4 v = *reinterpret_cast<const float4*>(Xsrc + (size_t)gr * HIDDEN + kc + c4);
            *reinterpret_cast<float4*>(&Xs[row * XS_STRIDE + c4]) = v;
        }
#pragma unroll
        for (int q = 0; q < 8; ++q) {
            int idx = q * 256 + tid;          // 0..2047
            int row = idx >> 5;
            int c4  = (idx & 31) * 4;
            float4 v = *reinterpret_cast<const float4*>(Wsrc + (size_t)(kc + row) * HIDDEN + c4);
            *reinterpret_cast<float4*>(&Ws[row * HIDDEN + c4]) = v;
        }
        __syncthreads();

#pragma unroll
        for (int kk = 0; kk < 64; kk += 4) {
            float4 xr[4];
#pragma unroll
            for (int m = 0; m < 4; ++m)
                xr[m] = *reinterpret_cast<const float4*>(&Xs[(ri * 4 + m) * XS_STRIDE + kk]);
#pragma unroll
            for (int j = 0; j < 4; ++j) {
                float4 w0 = *reinterpret_cast<const float4*>(&Ws[(kk + j) * HIDDEN + ci * 4]);
                float4 w1 = *reinterpret_cast<const float4*>(&Ws[(kk + j) * HIDDEN + 64 + ci * 4]);
#pragma unroll
                for (int m = 0; m < 4; ++m) {
                    float xm = (j == 0) ? xr[m].x : (j == 1) ? xr[m].y
                             : (j == 2) ? xr[m].z : xr[m].w;
                    acc[m][0] = fmaf(xm, w0.x, acc[m][0]);
                    acc[m][1] = fmaf(xm, w0.y, acc[m][1]);
                    acc[m][2] = fmaf(xm, w0.z, acc[m][2]);
                    acc[m][3] = fmaf(xm, w0.w, acc[m][3]);
                    acc[m][4] = fmaf(xm, w1.x, acc[m][4]);
                    acc[m][5] = fmaf(xm, w1.y, acc[m][5]);
                    acc[m][6] = fmaf(xm, w1.z, acc[m][6]);
                    acc[m][7] = fmaf(xm, w1.w, acc[m][7]);
                }
            }
        }
    }

    // epilogue: relu -> per-thread rank-8 partials vs LDS W3 -> width-16 shfl
    // reduce over the 16 ci-threads of each node -> z / out (h2 never stored)
    const float b30 = b3[0], b31 = b3[1], b32 = b3[2];
#pragma unroll
    for (int m = 0; m < 4; ++m) {
        int node = nb + ri * 4 + m;
        float zr0 = 0.f, zr1 = 0.f, zr2 = 0.f;
        float zo0 = 0.f, zo1 = 0.f, zo2 = 0.f;
#pragma unroll
        for (int jj = 0; jj < 4; ++jj) {
            float hv = fmaxf(acc[m][jj], 0.f);
            const float* w3 = &W3s[(ci * 4 + jj) * W3_STRIDE];
            zr0 = fmaf(hv, w3[0], zr0); zr1 = fmaf(hv, w3[1], zr1); zr2 = fmaf(hv, w3[2], zr2);
            zo0 = fmaf(hv, w3[3], zo0); zo1 = fmaf(hv, w3[4], zo1); zo2 = fmaf(hv, w3[5], zo2);
        }
#pragma unroll
        for (int jj = 0; jj < 4; ++jj) {
            float hv = fmaxf(acc[m][4 + jj], 0.f);
            const float* w3 = &W3s[(64 + ci * 4 + jj) * W3_STRIDE];
            zr0 = fmaf(hv, w3[0], zr0); zr1 = fmaf(hv, w3[1], zr1); zr2 = fmaf(hv, w3[2], zr2);
            zo0 = fmaf(hv, w3[3], zo0); zo1 = fmaf(hv, w3[4], zo1); zo2 = fmaf(hv, w3[5], zo2);
        }
#pragma unroll
        for (int d = 8; d >= 1; d >>= 1) {
            zr0 += __shfl_down(zr0, d, 16);
            zr1 += __shfl_down(zr1, d, 16);
            zr2 += __shfl_down(zr2, d, 16);
            zo0 += __shfl_down(zo0, d, 16);
            zo1 += __shfl_down(zo1, d, 16);
            zo2 += __shfl_down(zo2, d, 16);
        }
        if (ci == 0 && node < N) {
            z[(size_t)node * 3 + 0] = zr0;
            z[(size_t)node * 3 + 1] = zr1;
            z[(size_t)node * 3 + 2] = zr2;
            out[(size_t)node * 3 + 0] = zo0 + b30;
            out[(size_t)node * 3 + 1] = zo1 + b31;
            out[(size_t)node * 3 + 2] = zo2 + b32;
        }
    }
}

// ================= layer 3 gather =====================
__global__ __launch_bounds__(256)
void k_gather3(const int* __restrict__ offs, const int2* __restrict__ cpack,
               const float* __restrict__ z, float* __restrict__ out,
               int N, int E) {
    int i = blockIdx.x * 256 + threadIdx.x;
    if (i >= N) return;
    int start = offs[i], end = end_of(offs, i, N, E);
    float a0 = 0.f, a1 = 0.f, a2 = 0.f;
    for (int j = start; j < end; ++j) {
        int2  p = cpack[j];
        int   s = p.x;
        float w = __int_as_float(p.y);
        const float* zp = z + (size_t)s * 3;
        a0 = fmaf(w, zp[0], a0);
        a1 = fmaf(w, zp[1], a1);
        a2 = fmaf(w, zp[2], a2);
    }
    out[(size_t)i * 3 + 0] += a0;
    out[(size_t)i * 3 + 1] += a1;
    out[(size_t)i * 3 + 2] += a2;
}

extern "C" void kernel_launch(void* const* d_in, const int* in_sizes, int n_in,
                              void* d_out, int out_size, void* d_ws, size_t ws_size,
                              hipStream_t stream) {
    const float* x      = (const float*)d_in[0];
    const int*   ei     = (const int*)  d_in[1];
    const float* ew     = (const float*)d_in[2];
    const float* W1rel  = (const float*)d_in[4];
    const float* b1     = (const float*)d_in[5];
    const float* W1root = (const float*)d_in[6];
    const float* W2rel  = (const float*)d_in[7];
    const float* b2     = (const float*)d_in[8];
    const float* W2root = (const float*)d_in[9];
    const float* W3rel  = (const float*)d_in[10];
    const float* b3     = (const float*)d_in[11];
    const float* W3root = (const float*)d_in[12];
    float* out = (float*)d_out;

    const int N = in_sizes[0] / 2;
    const int E = in_sizes[2];
    const int* src = ei;
    const int* dst = ei + E;

    // -------- workspace layout --------
    // h     : N*128 f32   (h1; front E ints alias rank during CSR build)
    // aggr  : N*128 f32   (layer-2 aggregation; read-only in node2)
    // offs  : N int | bsum : SCAN_B int
    // cpack : E int2      (front N ints alias cnt — cnt dead before k_fill)
    // yv    : N float4    (combined (aggr1,x); dead after gatherfused —
    //         front N*3 f32 reused as z by node2/gather3)
    float* h    = (float*)d_ws;
    float* aggr = h + (size_t)N * HIDDEN;
    int*   offs = (int*)(aggr + (size_t)N * HIDDEN);
    int*   bsum = offs + N;
    size_t cpo  = (size_t)(bsum + SCAN_B - (int*)d_ws);
    cpo = (cpo + 1) & ~(size_t)1;          // 8B alignment
    int2*   cpack = (int2*)((int*)d_ws + cpo);
    size_t yvo  = (size_t)((char*)(cpack + E) - (char*)d_ws);
    yvo = (yvo + 15) & ~(size_t)15;        // 16B alignment
    float4* yv  = (float4*)((char*)d_ws + yvo);
    int* cnt  = (int*)cpack;               // alias: dead before k_fill writes cpack
    int* rank = (int*)h;                   // alias: dead before gatherfused writes h
    float* z  = (float*)yv;                // alias: yv dead after gatherfused

    const int nbScan = (N + SCAN_B - 1) / SCAN_B;

    // -------- CSR build --------
    hipMemsetAsync(cnt, 0, (size_t)N * sizeof(int), stream);
    k_hist <<<(E + 255) / 256, 256, 0, stream>>>(dst, cnt, rank, E);
    k_scan1<<<nbScan, SCAN_B, 0, stream>>>(cnt, offs, bsum, N);
    k_scan2<<<1, SCAN_B, 0, stream>>>(bsum, nbScan);
    k_scan3<<<nbScan, SCAN_B, 0, stream>>>(offs, bsum, N);
    k_fill <<<(E + 255) / 256, 256, 0, stream>>>(src, dst, ew, offs, rank, cpack, E);

    // -------- layer 1 aggregation (2ch) + y pack --------
    k_gather2<<<(N + 255) / 256, 256, 0, stream>>>(offs, cpack, x, yv, N, E);

    // -------- fused layer-2 aggregation + layer-1 node update --------
    {
        long long threads = (long long)N * 64;
        k_gatherfused<<<(int)((threads + 255) / 256), 256, 0, stream>>>(
            offs, cpack, yv, W1rel, b1, W1root, h, aggr, N, E);
    }

    // -------- fused layer-2 node update + layer-3 projection --------
    k_node2<<<(N + BM2 - 1) / BM2, 256, 0, stream>>>(
        aggr, h, W2rel, b2, W2root, W3rel, b3, W3root, z, out, N);

    // -------- layer 3 gather --------
    k_gather3<<<(N + 255) / 256, 256, 0, stream>>>(offs, cpack, z, out, N, E);
}

// Round 8
// 316.037 us; speedup vs baseline: 1.1183x; 1.0041x over previous
//
#include <hip/hip_runtime.h>

#define HIDDEN 128
#define SCAN_B 1024

typedef float v2f __attribute__((ext_vector_type(2)));
__device__ __forceinline__ v2f v2s(float a) { v2f r; r.x = a; r.y = a; return r; }

// ================= CSR build (per call; no fp atomics anywhere) =============
__global__ __launch_bounds__(256)
void k_hist(const int* __restrict__ dst, int* __restrict__ cnt,
            int* __restrict__ rank, int E) {
    int e = blockIdx.x * 256 + threadIdx.x;
    if (e < E) rank[e] = atomicAdd(&cnt[dst[e]], 1);
}

__global__ __launch_bounds__(SCAN_B)
void k_scan1(const int* __restrict__ cnt, int* __restrict__ offs,
             int* __restrict__ bsum, int N) {
    __shared__ int sm[SCAN_B];
    int g = blockIdx.x * SCAN_B + threadIdx.x;
    int v = (g < N) ? cnt[g] : 0;
    int acc = v;
    sm[threadIdx.x] = v;
    __syncthreads();
    for (int d = 1; d < SCAN_B; d <<= 1) {
        int t = (threadIdx.x >= d) ? sm[threadIdx.x - d] : 0;
        __syncthreads();
        acc += t;
        sm[threadIdx.x] = acc;
        __syncthreads();
    }
    if (g < N) offs[g] = acc - v;                 // exclusive
    if (threadIdx.x == SCAN_B - 1) bsum[blockIdx.x] = acc;
}

__global__ __launch_bounds__(SCAN_B)
void k_scan2(int* __restrict__ bsum, int nb) {
    __shared__ int sm[SCAN_B];
    int v = (threadIdx.x < nb) ? bsum[threadIdx.x] : 0;
    int acc = v;
    sm[threadIdx.x] = v;
    __syncthreads();
    for (int d = 1; d < SCAN_B; d <<= 1) {
        int t = (threadIdx.x >= d) ? sm[threadIdx.x - d] : 0;
        __syncthreads();
        acc += t;
        sm[threadIdx.x] = acc;
        __syncthreads();
    }
    if (threadIdx.x < nb) bsum[threadIdx.x] = acc - v;   // exclusive
}

__global__ __launch_bounds__(SCAN_B)
void k_scan3(int* __restrict__ offs, const int* __restrict__ bsum, int N) {
    int g = blockIdx.x * SCAN_B + threadIdx.x;
    if (g < N) offs[g] += bsum[blockIdx.x];
}

// Scatter edges into CSR order. One 8B packed store per edge (src, w).
__global__ __launch_bounds__(256)
void k_fill(const int* __restrict__ src, const int* __restrict__ dst,
            const float* __restrict__ ew, const int* __restrict__ offs,
            const int* __restrict__ rank, int2* __restrict__ cpack, int E) {
    int e = blockIdx.x * 256 + threadIdx.x;
    if (e >= E) return;
    int d = dst[e];
    int slot = offs[d] + rank[e];
    int2 p;
    p.x = src[e];
    p.y = __float_as_int(ew[e]);
    cpack[slot] = p;
}

__device__ __forceinline__ int end_of(const int* offs, int i, int N, int E) {
    return (i + 1 < N) ? offs[i + 1] : E;
}

// ================= layer 1: gather 2ch, emit combined y = (a0,a1,x0,x1) ====
__global__ __launch_bounds__(256)
void k_gather2(const int* __restrict__ offs, const int2* __restrict__ cpack,
               const float* __restrict__ x, float4* __restrict__ yv,
               int N, int E) {
    int i = blockIdx.x * 256 + threadIdx.x;
    if (i >= N) return;
    int start = offs[i], end = end_of(offs, i, N, E);
    float a0 = 0.f, a1 = 0.f;
    for (int j = start; j < end; ++j) {
        int2  p = cpack[j];
        int   s = p.x;
        float w = __int_as_float(p.y);
        float2 xv = *reinterpret_cast<const float2*>(x + (size_t)s * 2);
        a0 = fmaf(w, xv.x, a0);
        a1 = fmaf(w, xv.y, a1);
    }
    float2 xi = *reinterpret_cast<const float2*>(x + (size_t)i * 2);
    yv[i] = make_float4(a0, a1, xi.x, xi.y);
}

// ================= fused layer-2 aggregation + layer-1 node update ==========
// R5 structure (per-lane staging + shfl + packed v2f math), unroll deepened
// to an 8/4/1 cascade: avg degree = 16, so 8 independent yv loads in flight
// against the ~250cy shfl->load->math chain (R7 had only 4).
#define EDGE4(sK, wK)                                              \
    {                                                              \
        v2f t = B + v2s((sK).x) * WR0 + v2s((sK).y) * WR1          \
                  + v2s((sK).z) * WO0 + v2s((sK).w) * WO1;         \
        t = __builtin_elementwise_max(t, Z);                       \
        acc = acc + v2s(wK) * t;                                   \
    }

__global__ __launch_bounds__(256)
void k_gatherfused(const int* __restrict__ offs, const int2* __restrict__ cpack,
                   const float4* __restrict__ yv,
                   const float* __restrict__ W1rel, const float* __restrict__ b1,
                   const float* __restrict__ W1root,
                   float* __restrict__ h, float* __restrict__ aggr,
                   int N, int E) {
    int wv   = (blockIdx.x * 256 + threadIdx.x) >> 6;
    int lane = threadIdx.x & 63;
    if (wv >= N) return;

    const int c0 = lane * 2;
    const v2f WR0 = *reinterpret_cast<const v2f*>(W1rel  + c0);
    const v2f WR1 = *reinterpret_cast<const v2f*>(W1rel  + HIDDEN + c0);
    const v2f WO0 = *reinterpret_cast<const v2f*>(W1root + c0);
    const v2f WO1 = *reinterpret_cast<const v2f*>(W1root + HIDDEN + c0);
    const v2f B   = *reinterpret_cast<const v2f*>(b1 + c0);
    const v2f Z   = {0.f, 0.f};

    int start = offs[wv], end = end_of(offs, wv, N, E);
    v2f acc = {0.f, 0.f};

    for (int base = start; base < end; base += 64) {
        int nb = min(64, end - base);
        int sx = 0, wb = 0;
        if (lane < nb) {                       // one coalesced 8B/lane load
            int2 p = cpack[base + lane];
            sx = p.x; wb = p.y;
        }
        int k = 0;
        for (; k + 8 <= nb; k += 8) {          // 8 loads in flight
            int s0 = __shfl(sx, k),     s1 = __shfl(sx, k + 1);
            int s2 = __shfl(sx, k + 2), s3 = __shfl(sx, k + 3);
            int s4 = __shfl(sx, k + 4), s5 = __shfl(sx, k + 5);
            int s6 = __shfl(sx, k + 6), s7 = __shfl(sx, k + 7);
            float w0 = __int_as_float(__shfl(wb, k));
            float w1 = __int_as_float(__shfl(wb, k + 1));
            float w2 = __int_as_float(__shfl(wb, k + 2));
            float w3 = __int_as_float(__shfl(wb, k + 3));
            float w4 = __int_as_float(__shfl(wb, k + 4));
            float w5 = __int_as_float(__shfl(wb, k + 5));
            float w6 = __int_as_float(__shfl(wb, k + 6));
            float w7 = __int_as_float(__shfl(wb, k + 7));
            float4 y0 = yv[s0]; float4 y1 = yv[s1];
            float4 y2 = yv[s2]; float4 y3 = yv[s3];
            float4 y4 = yv[s4]; float4 y5 = yv[s5];
            float4 y6 = yv[s6]; float4 y7 = yv[s7];
            EDGE4(y0, w0) EDGE4(y1, w1) EDGE4(y2, w2) EDGE4(y3, w3)
            EDGE4(y4, w4) EDGE4(y5, w5) EDGE4(y6, w6) EDGE4(y7, w7)
        }
        for (; k + 4 <= nb; k += 4) {          // 4-deep middle tier
            int s0 = __shfl(sx, k),     s1 = __shfl(sx, k + 1);
            int s2 = __shfl(sx, k + 2), s3 = __shfl(sx, k + 3);
            float w0 = __int_as_float(__shfl(wb, k));
            float w1 = __int_as_float(__shfl(wb, k + 1));
            float w2 = __int_as_float(__shfl(wb, k + 2));
            float w3 = __int_as_float(__shfl(wb, k + 3));
            float4 y0 = yv[s0]; float4 y1 = yv[s1];
            float4 y2 = yv[s2]; float4 y3 = yv[s3];
            EDGE4(y0, w0) EDGE4(y1, w1) EDGE4(y2, w2) EDGE4(y3, w3)
        }
        for (; k < nb; ++k) {                  // scalar tail (<=3)
            int   s0 = __shfl(sx, k);
            float w0 = __int_as_float(__shfl(wb, k));
            float4 y0 = yv[s0];
            EDGE4(y0, w0)
        }
    }

    *reinterpret_cast<v2f*>(aggr + (size_t)wv * HIDDEN + c0) = acc;

    // fused k_node1: this wave's own h1 row
    {
        float4 y = yv[wv];
        v2f t = B + v2s(y.x) * WR0 + v2s(y.y) * WR1
                  + v2s(y.z) * WO0 + v2s(y.w) * WO1;
        t = __builtin_elementwise_max(t, Z);
        *reinterpret_cast<v2f*>(h + (size_t)wv * HIDDEN + c0) = t;
    }
}

// ============ fused layer-2 node update + layer-3 projection ================
// R7 structure, with Xs pad replaced by an XOR swizzle (col ^= (row&15)<<2):
//   - LDS 53760 -> 52736 B: safely under 160KB/3 even with coarse allocation
//     granularity -> 3 blocks/CU (R7's 53760 measured at ~2 blocks/CU).
//   - read banks: the 4 ri-lanes hit rows {m,m+4,m+8,m+12} -> 4 distinct
//     (row&15) -> 4 distinct banks, conflict-free; ci-lanes broadcast.
// h2 = relu([aggr | h] @ [W2rel ; W2root] + b2)   (registers only)
// z  = h2 @ W3rel ; out = h2 @ W3root + b3
#define BM2 64
#define W3_STRIDE 7    // stride 6 -> 4-way bank conflict; 7 -> 2-way (free)
#define XSW(row, col) ((row) * 64 + ((col) ^ (((row) & 15) << 2)))

__global__ __launch_bounds__(256)
void k_node2(const float* __restrict__ aggr, const float* __restrict__ h,
             const float* __restrict__ Wrel, const float* __restrict__ b,
             const float* __restrict__ Wroot,
             const float* __restrict__ W3rel, const float* __restrict__ b3,
             const float* __restrict__ W3root,
             float* __restrict__ z, float* __restrict__ out, int N) {
    __shared__ float Xs[BM2 * 64];            // 64 x 64 swizzled, 16.4KB
    __shared__ float Ws[64 * HIDDEN];         // 64 x 128 weight tile, 32.8KB
    __shared__ float W3s[HIDDEN * W3_STRIDE]; // 3.6KB

    const int tid = threadIdx.x;
    const int ci  = tid & 15;                 // channel group: cols ci*4, 64+ci*4
    const int ri  = tid >> 4;                 // node group: rows ri*4 .. ri*4+3
    const int nb  = blockIdx.x * BM2;

    // preload W3 (tiny, once) — ordered by the first __syncthreads below
    if (tid < HIDDEN) {
#pragma unroll
        for (int c = 0; c < 3; ++c) {
            W3s[tid * W3_STRIDE + c]     = W3rel [tid * 3 + c];
            W3s[tid * W3_STRIDE + 3 + c] = W3root[tid * 3 + c];
        }
    }

    float acc[4][8];
    {
        float4 b0 = *reinterpret_cast<const float4*>(b + ci * 4);
        float4 b1 = *reinterpret_cast<const float4*>(b + 64 + ci * 4);
#pragma unroll
        for (int m = 0; m < 4; ++m) {
            acc[m][0] = b0.x; acc[m][1] = b0.y; acc[m][2] = b0.z; acc[m][3] = b0.w;
            acc[m][4] = b1.x; acc[m][5] = b1.y; acc[m][6] = b1.z; acc[m][7] = b1.w;
        }
    }

    // K = 256 total: tiles 0,1 = aggr @ Wrel; tiles 2,3 = h @ Wroot.
    for (int t = 0; t < 4; ++t) {
        const float* Xsrc = (t < 2) ? aggr : h;
        const float* Wsrc = (t < 2) ? Wrel : Wroot;
        const int kc = (t & 1) * 64;

        __syncthreads();                      // previous compute done before overwrite
#pragma unroll
        for (int q = 0; q < 4; ++q) {
            int idx = q * 256 + tid;          // 0..1023
            int row = idx >> 4;
            int c4  = (idx & 15) * 4;
            int gr  = nb + row; if (gr >= N) gr = N - 1;
            float4 v = *reinterpret_cast<const float4*>(Xsrc + (size_t)gr * HIDDEN + kc + c4);
            *reinterpret_cast<float4*>(&Xs[XSW(row, c4)]) = v;
        }
#pragma unroll
        for (int q = 0; q < 8; ++q) {
            int idx = q * 256 + tid;          // 0..2047
            int row = idx >> 5;
            int c4  = (idx & 31) * 4;
            float4 v = *reinterpret_cast<const float4*>(Wsrc + (size_t)(kc + row) * HIDDEN + c4);
            *reinterpret_cast<float4*>(&Ws[row * HIDDEN + c4]) = v;
        }
        __syncthreads();

#pragma unroll
        for (int kk = 0; kk < 64; kk += 4) {
            float4 xr[4];
#pragma unroll
            for (int m = 0; m < 4; ++m) {
                int r = ri * 4 + m;
                xr[m] = *reinterpret_cast<const float4*>(&Xs[XSW(r, kk)]);
            }
#pragma unroll
            for (int j = 0; j < 4; ++j) {
                float4 w0 = *reinterpret_cast<const float4*>(&Ws[(kk + j) * HIDDEN + ci * 4]);
                float4 w1 = *reinterpret_cast<const float4*>(&Ws[(kk + j) * HIDDEN + 64 + ci * 4]);
#pragma unroll
                for (int m = 0; m < 4; ++m) {
                    float xm = (j == 0) ? xr[m].x : (j == 1) ? xr[m].y
                             : (j == 2) ? xr[m].z : xr[m].w;
                    acc[m][0] = fmaf(xm, w0.x, acc[m][0]);
                    acc[m][1] = fmaf(xm, w0.y, acc[m][1]);
                    acc[m][2] = fmaf(xm, w0.z, acc[m][2]);
                    acc[m][3] = fmaf(xm, w0.w, acc[m][3]);
                    acc[m][4] = fmaf(xm, w1.x, acc[m][4]);
                    acc[m][5] = fmaf(xm, w1.y, acc[m][5]);
                    acc[m][6] = fmaf(xm, w1.z, acc[m][6]);
                    acc[m][7] = fmaf(xm, w1.w, acc[m][7]);
                }
            }
        }
    }

    // epilogue: relu -> per-thread rank-8 partials vs LDS W3 -> width-16 shfl
    // reduce over the 16 ci-threads of each node -> z / out (h2 never stored)
    const float b30 = b3[0], b31 = b3[1], b32 = b3[2];
#pragma unroll
    for (int m = 0; m < 4; ++m) {
        int node = nb + ri * 4 + m;
        float zr0 = 0.f, zr1 = 0.f, zr2 = 0.f;
        float zo0 = 0.f, zo1 = 0.f, zo2 = 0.f;
#pragma unroll
        for (int jj = 0; jj < 4; ++jj) {
            float hv = fmaxf(acc[m][jj], 0.f);
            const float* w3 = &W3s[(ci * 4 + jj) * W3_STRIDE];
            zr0 = fmaf(hv, w3[0], zr0); zr1 = fmaf(hv, w3[1], zr1); zr2 = fmaf(hv, w3[2], zr2);
            zo0 = fmaf(hv, w3[3], zo0); zo1 = fmaf(hv, w3[4], zo1); zo2 = fmaf(hv, w3[5], zo2);
        }
#pragma unroll
        for (int jj = 0; jj < 4; ++jj) {
            float hv = fmaxf(acc[m][4 + jj], 0.f);
            const float* w3 = &W3s[(64 + ci * 4 + jj) * W3_STRIDE];
            zr0 = fmaf(hv, w3[0], zr0); zr1 = fmaf(hv, w3[1], zr1); zr2 = fmaf(hv, w3[2], zr2);
            zo0 = fmaf(hv, w3[3], zo0); zo1 = fmaf(hv, w3[4], zo1); zo2 = fmaf(hv, w3[5], zo2);
        }
#pragma unroll
        for (int d = 8; d >= 1; d >>= 1) {
            zr0 += __shfl_down(zr0, d, 16);
            zr1 += __shfl_down(zr1, d, 16);
            zr2 += __shfl_down(zr2, d, 16);
            zo0 += __shfl_down(zo0, d, 16);
            zo1 += __shfl_down(zo1, d, 16);
            zo2 += __shfl_down(zo2, d, 16);
        }
        if (ci == 0 && node < N) {
            z[(size_t)node * 3 + 0] = zr0;
            z[(size_t)node * 3 + 1] = zr1;
            z[(size_t)node * 3 + 2] = zr2;
            out[(size_t)node * 3 + 0] = zo0 + b30;
            out[(size_t)node * 3 + 1] = zo1 + b31;
            out[(size_t)node * 3 + 2] = zo2 + b32;
        }
    }
}

// ================= layer 3 gather =====================
__global__ __launch_bounds__(256)
void k_gather3(const int* __restrict__ offs, const int2* __restrict__ cpack,
               const float* __restrict__ z, float* __restrict__ out,
               int N, int E) {
    int i = blockIdx.x * 256 + threadIdx.x;
    if (i >= N) return;
    int start = offs[i], end = end_of(offs, i, N, E);
    float a0 = 0.f, a1 = 0.f, a2 = 0.f;
    for (int j = start; j < end; ++j) {
        int2  p = cpack[j];
        int   s = p.x;
        float w = __int_as_float(p.y);
        const float* zp = z + (size_t)s * 3;
        a0 = fmaf(w, zp[0], a0);
        a1 = fmaf(w, zp[1], a1);
        a2 = fmaf(w, zp[2], a2);
    }
    out[(size_t)i * 3 + 0] += a0;
    out[(size_t)i * 3 + 1] += a1;
    out[(size_t)i * 3 + 2] += a2;
}

extern "C" void kernel_launch(void* const* d_in, const int* in_sizes, int n_in,
                              void* d_out, int out_size, void* d_ws, size_t ws_size,
                              hipStream_t stream) {
    const float* x      = (const float*)d_in[0];
    const int*   ei     = (const int*)  d_in[1];
    const float* ew     = (const float*)d_in[2];
    const float* W1rel  = (const float*)d_in[4];
    const float* b1     = (const float*)d_in[5];
    const float* W1root = (const float*)d_in[6];
    const float* W2rel  = (const float*)d_in[7];
    const float* b2     = (const float*)d_in[8];
    const float* W2root = (const float*)d_in[9];
    const float* W3rel  = (const float*)d_in[10];
    const float* b3     = (const float*)d_in[11];
    const float* W3root = (const float*)d_in[12];
    float* out = (float*)d_out;

    const int N = in_sizes[0] / 2;
    const int E = in_sizes[2];
    const int* src = ei;
    const int* dst = ei + E;

    // -------- workspace layout --------
    // h     : N*128 f32   (h1; front E ints alias rank during CSR build)
    // aggr  : N*128 f32   (layer-2 aggregation; read-only in node2)
    // offs  : N int | bsum : SCAN_B int
    // cpack : E int2      (front N ints alias cnt — cnt dead before k_fill)
    // yv    : N float4    (combined (aggr1,x); dead after gatherfused —
    //         front N*3 f32 reused as z by node2/gather3)
    float* h    = (float*)d_ws;
    float* aggr = h + (size_t)N * HIDDEN;
    int*   offs = (int*)(aggr + (size_t)N * HIDDEN);
    int*   bsum = offs + N;
    size_t cpo  = (size_t)(bsum + SCAN_B - (int*)d_ws);
    cpo = (cpo + 1) & ~(size_t)1;          // 8B alignment
    int2*   cpack = (int2*)((int*)d_ws + cpo);
    size_t yvo  = (size_t)((char*)(cpack + E) - (char*)d_ws);
    yvo = (yvo + 15) & ~(size_t)15;        // 16B alignment
    float4* yv  = (float4*)((char*)d_ws + yvo);
    int* cnt  = (int*)cpack;               // alias: dead before k_fill writes cpack
    int* rank = (int*)h;                   // alias: dead before gatherfused writes h
    float* z  = (float*)yv;                // alias: yv dead after gatherfused

    const int nbScan = (N + SCAN_B - 1) / SCAN_B;

    // -------- CSR build --------
    hipMemsetAsync(cnt, 0, (size_t)N * sizeof(int), stream);
    k_hist <<<(E + 255) / 256, 256, 0, stream>>>(dst, cnt, rank, E);
    k_scan1<<<nbScan, SCAN_B, 0, stream>>>(cnt, offs, bsum, N);
    k_scan2<<<1, SCAN_B, 0, stream>>>(bsum, nbScan);
    k_scan3<<<nbScan, SCAN_B, 0, stream>>>(offs, bsum, N);
    k_fill <<<(E + 255) / 256, 256, 0, stream>>>(src, dst, ew, offs, rank, cpack, E);

    // -------- layer 1 aggregation (2ch) + y pack --------
    k_gather2<<<(N + 255) / 256, 256, 0, stream>>>(offs, cpack, x, yv, N, E);

    // -------- fused layer-2 aggregation + layer-1 node update --------
    {
        long long threads = (long long)N * 64;
        k_gatherfused<<<(int)((threads + 255) / 256), 256, 0, stream>>>(
            offs, cpack, yv, W1rel, b1, W1root, h, aggr, N, E);
    }

    // -------- fused layer-2 node update + layer-3 projection --------
    k_node2<<<(N + BM2 - 1) / BM2, 256, 0, stream>>>(
        aggr, h, W2rel, b2, W2root, W3rel, b3, W3root, z, out, N);

    // -------- layer 3 gather --------
    k_gather3<<<(N + 255) / 256, 256, 0, stream>>>(offs, cpack, z, out, N, E);
}